// Round 6
// baseline (216.487 us; speedup 1.0000x reference)
//
#include <hip/hip_runtime.h>

// IPUNeighborListMD — dense masked displacement matrix.
// out[m,i,j,c] = (pos[m,j,c] - pos[m,i,c]) * (|r_j - r_i|^2 < 49 && i != j)
// out: [64, 512, 512, 3] f32 (192 MiB) -> pure write-BW problem (~30 us floor
// at the fill kernel's demonstrated 6.6 TB/s).
//
// R6: fill-kernel-shaped. One block per output row (i), 384 threads; thread c
// produces output float4 chunk c of the row entirely in registers:
//   floats [4c, 4c+4) lie inside atoms ja=floor(4c/3), ja+1 -> load those 6
//   floats once, compute keep(i,ja), keep(i,ja+1), select chunk/comps/masks
//   by c%3 (mapping bit-exact-verified in R5), one coalesced 16 B store.
// No LDS, no barriers, no register arrays -> low VGPR, 8 waves/SIMD,
// 32768 lightweight blocks. dur_us includes ~150 us of harness poison fills.

#define NMOL   64
#define NATOM  512
#define RC2    49.0f      // (5.0 + 2.0)^2, exact in f32

typedef unsigned int   u32;
typedef unsigned short u16;

__device__ __forceinline__ float bf2f(u16 u) {
    union { u32 u; float f; } v; v.u = ((u32)u) << 16; return v.f;
}

__global__ __launch_bounds__(384)
void nbl_kernel(const void* __restrict__ pos_raw, float* __restrict__ out) {
    const int t    = threadIdx.x;
    const int lane = t & 63;

    // ---- dtype sniff, wave-uniform (all waves probe the same 128 words) ----
    // f32 in [0,20): byte1 is random mantissa (often > 0x41); packed-bf16
    // byte1 is a bf16-high-byte of a value in [0,20) (always <= 0x41).
    const u32* w = (const u32*)pos_raw;
    const u32 wa = w[lane];
    const u32 wb = w[lane + 128];
    const bool is_f32 = __any((int)(((( wa >> 8) & 0xffu) > 0x41u) |
                                    ((( wb >> 8) & 0xffu) > 0x41u)));

    const int bx = blockIdx.x;
    const int m  = bx >> 9;           // molecule
    const int i  = bx & (NATOM - 1);  // row atom
    const int c  = t;                 // chunk 0..383 (row = 384 float4)
    const int ja = (4 * c) / 3;       // first atom touched by the chunk
    const int cm = c % 3;

    const float* pm32 = (const float*)pos_raw + (size_t)m * (NATOM * 3);
    const u16*   pm16 = (const u16*)pos_raw   + (size_t)m * (NATOM * 3);

    float rx, ry, rz;                 // atom i (block-uniform -> scalar loads)
    float p0, p1, p2, p3, p4, p5;     // atoms ja (p0..p2), ja+1 (p3..p5)
    if (is_f32) {
        rx = pm32[3*i+0]; ry = pm32[3*i+1]; rz = pm32[3*i+2];
        const float* pa = pm32 + 3 * ja;       // ja<=510 -> pa[5] in-bounds
        p0 = pa[0]; p1 = pa[1]; p2 = pa[2]; p3 = pa[3]; p4 = pa[4]; p5 = pa[5];
    } else {
        rx = bf2f(pm16[3*i+0]); ry = bf2f(pm16[3*i+1]); rz = bf2f(pm16[3*i+2]);
        const u16* pa = pm16 + 3 * ja;
        p0 = bf2f(pa[0]); p1 = bf2f(pa[1]); p2 = bf2f(pa[2]);
        p3 = bf2f(pa[3]); p4 = bf2f(pa[4]); p5 = bf2f(pa[5]);
    }

    // ---- keep(i, ja) and keep(i, ja+1); exact numpy f32 semantics:
    // rounded sub/mul, sequential rounded adds ((x+y)+z), NO fma. ----
    const float dax = __fsub_rn(p0, rx);
    const float day = __fsub_rn(p1, ry);
    const float daz = __fsub_rn(p2, rz);
    const float d2a = __fadd_rn(__fadd_rn(__fmul_rn(dax, dax),
                                          __fmul_rn(day, day)),
                                __fmul_rn(daz, daz));
    const float ka = ((d2a < RC2) && (ja != i)) ? 1.0f : 0.0f;

    const float dbx = __fsub_rn(p3, rx);
    const float dby = __fsub_rn(p4, ry);
    const float dbz = __fsub_rn(p5, rz);
    const float d2b = __fadd_rn(__fadd_rn(__fmul_rn(dbx, dbx),
                                          __fmul_rn(dby, dby)),
                                __fmul_rn(dbz, dbz));
    const float kb = ((d2b < RC2) && ((ja + 1) != i)) ? 1.0f : 0.0f;

    // ---- chunk floats / subtrahend comps / masks, selected by cm ----
    // cm=0: floats(p0,p1,p2,p3) comps(x,y,z,x) masks(ka,ka,ka,kb)
    // cm=1: floats(p1,p2,p3,p4) comps(y,z,x,y) masks(ka,ka,kb,kb)
    // cm=2: floats(p2,p3,p4,p5) comps(z,x,y,z) masks(ka,kb,kb,kb)
    const float f0 = (cm == 0) ? p0 : ((cm == 1) ? p1 : p2);
    const float f1 = (cm == 0) ? p1 : ((cm == 1) ? p2 : p3);
    const float f2 = (cm == 0) ? p2 : ((cm == 1) ? p3 : p4);
    const float f3 = (cm == 0) ? p3 : ((cm == 1) ? p4 : p5);
    const float r0 = (cm == 0) ? rx : ((cm == 1) ? ry : rz);
    const float r1 = (cm == 0) ? ry : ((cm == 1) ? rz : rx);
    const float r2 = (cm == 0) ? rz : ((cm == 1) ? rx : ry);
    const float m0 = ka;
    const float m1 = (cm == 2) ? kb : ka;
    const float m2 = (cm == 0) ? ka : kb;
    const float m3 = kb;

    float4 o;
    o.x = __fmul_rn(__fsub_rn(f0, r0), m0);
    o.y = __fmul_rn(__fsub_rn(f1, r1), m1);
    o.z = __fmul_rn(__fsub_rn(f2, r2), m2);
    o.w = __fmul_rn(__fsub_rn(f3, r0), m3);

    ((float4*)out)[(size_t)bx * 384 + c] = o;
}

extern "C" void kernel_launch(void* const* d_in, const int* in_sizes, int n_in,
                              void* d_out, int out_size, void* d_ws, size_t ws_size,
                              hipStream_t stream) {
    const void* pos = d_in[0];
    float* out = (float*)d_out;
    dim3 grid(NMOL * NATOM);    // 32768 blocks, one per output row
    dim3 block(384);            // one float4 chunk per thread
    nbl_kernel<<<grid, block, 0, stream>>>(pos, out);
}

// Round 7
// 192.713 us; speedup vs baseline: 1.1234x; 1.1234x over previous
//
#include <hip/hip_runtime.h>

// IPUNeighborListMD — dense masked displacement matrix.
// out[m,i,j,c] = (pos[m,j,c] - pos[m,i,c]) * (|r_j - r_i|^2 < 49 && i != j)
// out: [64, 512, 512, 3] f32 (192 MiB) -> write-BW bound (~30 us floor at the
// harness fill kernels' demonstrated 6.7 TB/s).
//
// History: R2 220us (96B-stride stores) -> R3 194us (LDS transpose, coalesced)
// -> R4 203us (nt stores: slight regression) -> R5 193us (register-sourced
// stores, keep-vector-only LDS) -> R6 216us (fill-shaped scalar-load kernel:
// regression; proves per-thread load latency matters, structure near floor).
// R3 ~= R5 across opposite structures => external floor: dur_us includes
// ~160us of harness poison fills (768 MiB d_ws @ ~120us + 192 MiB d_out
// @ ~30us, visible in rocprof); kernel itself ~33us vs 30.5us write roofline.
// R7 = R5 verbatim (best measured, bit-exact).

#define NMOL   64
#define NATOM  512
#define RC2    49.0f      // (5.0 + 2.0)^2, exact in f32
#define SLICES 64         // blocks per molecule; 8 rows/block, 2 rows/wave

typedef unsigned int   u32;
typedef unsigned short u16;

__device__ __forceinline__ float bf2f(u16 u) {
    union { u32 u; float f; } v; v.u = ((u32)u) << 16; return v.f;
}

__global__ __launch_bounds__(256)
void nbl_kernel(const void* __restrict__ pos_raw, float* __restrict__ out) {
    __shared__ float s_keep[4][NATOM];   // per-wave keep vector, 2 KB each
    __shared__ int s_f32;
    const int t = threadIdx.x;

    // ---- input dtype sniff (f32 vs packed bf16), block-uniform result ----
    if (t == 0) s_f32 = 0;
    __syncthreads();
    {
        const u32* w = (const u32*)pos_raw;
        const u32 a = w[t];
        const u32 b = w[t + 256];
        if ((((a >> 8) & 0xffu) > 0x41u) || (((b >> 8) & 0xffu) > 0x41u))
            s_f32 = 1;   // benign same-value race
    }
    __syncthreads();
    const bool is_f32 = (s_f32 != 0);

    const int bx     = blockIdx.x;
    const int m      = bx >> 6;                 // molecule
    const int slice  = bx & (SLICES - 1);
    const int lane   = t & 63;
    const int wave   = t >> 6;
    const int i_base = slice * 8 + wave * 2;    // 4 waves x 2 rows = 8 rows

    const float* pm32 = (const float*)pos_raw + (size_t)m * (NATOM * 3);
    const u16*   pm16 = (const u16*)pos_raw   + (size_t)m * (NATOM * 3);

    // ---- prologue: all global loads, both dtype paths ----
    float pj[24];   // lane's 8 consecutive atoms j (phase-1 d2 source)
    float pc[24];   // lane's 6 output chunks c=64k+lane (phase-2 store source)
    float ri[6];    // this wave's 2 row atoms (wave-uniform)
    if (is_f32) {
        const float4* p4 = (const float4*)pm32 + lane * 6;
        #pragma unroll
        for (int k = 0; k < 6; ++k) {
            const float4 q = p4[k];
            pj[4*k+0] = q.x; pj[4*k+1] = q.y; pj[4*k+2] = q.z; pj[4*k+3] = q.w;
        }
        const float4* c4 = (const float4*)pm32;
        #pragma unroll
        for (int k = 0; k < 6; ++k) {
            const float4 q = c4[64*k + lane];
            pc[4*k+0] = q.x; pc[4*k+1] = q.y; pc[4*k+2] = q.z; pc[4*k+3] = q.w;
        }
        #pragma unroll
        for (int r = 0; r < 2; ++r) {
            const int i = i_base + r;
            ri[3*r+0] = pm32[3*i+0]; ri[3*r+1] = pm32[3*i+1]; ri[3*r+2] = pm32[3*i+2];
        }
    } else {
        const uint4* p4 = (const uint4*)pm16 + lane * 3;
        u32 words[12];
        #pragma unroll
        for (int k = 0; k < 3; ++k) {
            const uint4 q = p4[k];
            words[4*k+0] = q.x; words[4*k+1] = q.y;
            words[4*k+2] = q.z; words[4*k+3] = q.w;
        }
        #pragma unroll
        for (int k = 0; k < 12; ++k) {
            pj[2*k]   = bf2f((u16)(words[k] & 0xffffu));
            pj[2*k+1] = bf2f((u16)(words[k] >> 16));
        }
        const uint2* c2 = (const uint2*)pm16;
        #pragma unroll
        for (int k = 0; k < 6; ++k) {
            const uint2 q = c2[64*k + lane];
            pc[4*k+0] = bf2f((u16)(q.x & 0xffffu));
            pc[4*k+1] = bf2f((u16)(q.x >> 16));
            pc[4*k+2] = bf2f((u16)(q.y & 0xffffu));
            pc[4*k+3] = bf2f((u16)(q.y >> 16));
        }
        #pragma unroll
        for (int r = 0; r < 2; ++r) {
            const int i = i_base + r;
            ri[3*r+0] = bf2f(pm16[3*i+0]);
            ri[3*r+1] = bf2f(pm16[3*i+1]);
            ri[3*r+2] = bf2f(pm16[3*i+2]);
        }
    }

    // row-invariant chunk indexing: c = 64k+lane, cm = c%3, ja = floor(4c/3)
    int cms[6], jas[6];
    #pragma unroll
    for (int k = 0; k < 6; ++k) {
        const int c = 64 * k + lane;
        cms[k] = c % 3;
        jas[k] = (4 * c) / 3;     // compiler magic-mul
    }

    const int j0 = lane * 8;
    float* kw = s_keep[wave];

    #pragma unroll
    for (int r = 0; r < 2; ++r) {
        const int i = i_base + r;
        const float rx = ri[3*r+0], ry = ri[3*r+1], rz = ri[3*r+2];

        // ---- phase 1: keep[j] for lane's 8 atoms, atom-major ----
        float kv[8];
        #pragma unroll
        for (int jj = 0; jj < 8; ++jj) {
            // Exact numpy f32 semantics: rounded sub/mul, sequential rounded
            // adds ((x+y)+z), NO fma contraction (cutoff-boundary mask!).
            const float dx = __fsub_rn(pj[3*jj+0], rx);
            const float dy = __fsub_rn(pj[3*jj+1], ry);
            const float dz = __fsub_rn(pj[3*jj+2], rz);
            const float d2 = __fadd_rn(__fadd_rn(__fmul_rn(dx, dx),
                                                 __fmul_rn(dy, dy)),
                                       __fmul_rn(dz, dz));
            kv[jj] = ((d2 < RC2) && ((j0 + jj) != i)) ? 1.0f : 0.0f;
        }
        float4* kw4 = (float4*)(kw + j0);
        kw4[0] = make_float4(kv[0], kv[1], kv[2], kv[3]);
        kw4[1] = make_float4(kv[4], kv[5], kv[6], kv[7]);
        // same-wave ds ordering: writes complete before reads below (lgkmcnt)

        // ---- phase 2: f-major stores straight from registers ----
        const size_t row = (size_t)(m * NATOM + i);
        float4* ob = (float4*)out + row * 384;
        #pragma unroll
        for (int k = 0; k < 6; ++k) {
            const int cm = cms[k];
            const int ja = jas[k];
            const float ka = kw[ja];        // ds_read2_b32 pair
            const float kb = kw[ja + 1];
            // comps(t) = (c+t)%3 ; j bumps a->b when cm+t >= 3
            const float r0 = (cm == 0) ? rx : ((cm == 1) ? ry : rz);
            const float r1 = (cm == 0) ? ry : ((cm == 1) ? rz : rx);
            const float r2 = (cm == 0) ? rz : ((cm == 1) ? rx : ry);
            const float m0 = ka;
            const float m1 = (cm == 2) ? kb : ka;
            const float m2 = (cm == 0) ? ka : kb;
            const float m3 = kb;
            float4 o;
            o.x = __fmul_rn(__fsub_rn(pc[4*k+0], r0), m0);
            o.y = __fmul_rn(__fsub_rn(pc[4*k+1], r1), m1);
            o.z = __fmul_rn(__fsub_rn(pc[4*k+2], r2), m2);
            o.w = __fmul_rn(__fsub_rn(pc[4*k+3], r0), m3);
            ob[64 * k + lane] = o;
        }
    }
}

extern "C" void kernel_launch(void* const* d_in, const int* in_sizes, int n_in,
                              void* d_out, int out_size, void* d_ws, size_t ws_size,
                              hipStream_t stream) {
    const void* pos = d_in[0];
    float* out = (float*)d_out;
    dim3 grid(NMOL * SLICES);   // 4096 blocks
    dim3 block(256);
    nbl_kernel<<<grid, block, 0, stream>>>(pos, out);
}